// Round 1
// baseline (11922.658 us; speedup 1.0000x reference)
//
#include <hip/hip_runtime.h>
#include <hip/hip_fp16.h>

#define Bb 128
#define Tt 1024
#define Ii 256
#define Hh 512
#define Cc 10

#define HG   16          // column groups (32 cols each)
#define NBLK 64          // 16 hg x 4 bg
#define COLS 32          // output cols per block
#define ROWS 32          // batch rows per block
#define LDP  520         // padded fp16 leading dim for K=512 (1040B: conflict-free b128)
#define LDPI 264         // padded for K=256

typedef _Float16 f16;
typedef _Float16 f16x8 __attribute__((ext_vector_type(8)));
typedef _Float16 f16x4 __attribute__((ext_vector_type(4)));
typedef float    f32x4 __attribute__((ext_vector_type(4)));

static __device__ __forceinline__ f32x4 mfma16(f16x8 a, f16x8 b, f32x4 c) {
  return __builtin_amdgcn_mfma_f32_16x16x32_f16(a, b, c, 0, 0, 0);
}

static __device__ __forceinline__ float fast_tanh(float v) {
  float e = __expf(2.0f * v);          // v_exp_f32 based; saturates correctly at +/-inf
  return 1.0f - 2.0f / (e + 1.0f);
}

__global__ __launch_bounds__(256, 1) void rnn_persistent(
    const float* __restrict__ x,
    const float* __restrict__ w_ih1, const float* __restrict__ w_hh1,
    const float* __restrict__ b_ih1, const float* __restrict__ b_hh1,
    const float* __restrict__ w_ih2, const float* __restrict__ w_hh2,
    const float* __restrict__ b_ih2, const float* __restrict__ b_hh2,
    const float* __restrict__ w_out, const float* __restrict__ b_out,
    float* __restrict__ out,
    unsigned* __restrict__ cnt,
    f16* __restrict__ h1base,        // 2 x [128][512] fp16 ping-pong
    f16* __restrict__ h2base)        // 2 x [128][512] fp16 ping-pong
{
  __shared__ __align__(16) f16 ls_whh1[COLS][LDP];
  __shared__ __align__(16) f16 ls_wih2[COLS][LDP];
  __shared__ __align__(16) f16 ls_whh2[COLS][LDP];
  __shared__ __align__(16) f16 ls_wih1[COLS][LDPI];
  __shared__ float ls_b1[COLS], ls_b2[COLS];

  const int hg   = blockIdx.x & (HG - 1);
  const int bg   = blockIdx.x >> 4;
  const int col0 = hg * COLS;        // global output-column base
  const int row0 = bg * ROWS;        // global batch-row base

  // ---- one-time weight staging: fp32 global -> fp16 LDS (padded) ----
  for (int v = threadIdx.x; v < COLS * (Hh / 4); v += 256) {
    const int j  = v >> 7;           // local col (0..31)
    const int k4 = v & 127;          // float4 index along K
    const int gj = col0 + j;
    float4 a;
    a = ((const float4*)w_hh1)[gj * (Hh / 4) + k4];
    { f16x4 h = { (f16)a.x, (f16)a.y, (f16)a.z, (f16)a.w };
      *(f16x4*)&ls_whh1[j][k4 * 4] = h; }
    a = ((const float4*)w_ih2)[gj * (Hh / 4) + k4];
    { f16x4 h = { (f16)a.x, (f16)a.y, (f16)a.z, (f16)a.w };
      *(f16x4*)&ls_wih2[j][k4 * 4] = h; }
    a = ((const float4*)w_hh2)[gj * (Hh / 4) + k4];
    { f16x4 h = { (f16)a.x, (f16)a.y, (f16)a.z, (f16)a.w };
      *(f16x4*)&ls_whh2[j][k4 * 4] = h; }
  }
  for (int v = threadIdx.x; v < COLS * (Ii / 4); v += 256) {
    const int j  = v >> 6;
    const int k4 = v & 63;
    float4 a = ((const float4*)w_ih1)[(col0 + j) * (Ii / 4) + k4];
    f16x4 h = { (f16)a.x, (f16)a.y, (f16)a.z, (f16)a.w };
    *(f16x4*)&ls_wih1[j][k4 * 4] = h;
  }
  if (threadIdx.x < COLS) {
    ls_b1[threadIdx.x] = b_ih1[col0 + threadIdx.x] + b_hh1[col0 + threadIdx.x];
    ls_b2[threadIdx.x] = b_ih2[col0 + threadIdx.x] + b_hh2[col0 + threadIdx.x];
  }
  __syncthreads();

  // ---- per-thread fragment geometry (16x16x32 MFMA) ----
  const int wid  = threadIdx.x >> 6;
  const int lane = threadIdx.x & 63;
  const int wr   = wid >> 1;               // wave row-half (0/1)
  const int wc   = wid & 1;                // wave col-half (0/1)
  const int lm   = lane & 15;
  const int lk8  = (lane >> 4) * 8;        // k sub-offset within fragment
  const int arow = row0 + wr * 16 + lm;    // A-frag global batch row
  const int lcol = wc * 16 + lm;           // B-frag local col
  const float bias1 = ls_b1[lcol];
  const float bias2 = ls_b2[lcol];
  const int drow0 = row0 + wr * 16 + (lane >> 4) * 4;  // D rows: +r (0..3)
  const int dcol  = col0 + lcol;                       // D col
  const size_t HB = (size_t)Bb * Hh;

  // ---- pipelined recurrence: phase p computes h1_p and h2_{p-1} ----
  for (int p = 0; p <= Tt; ++p) {
    const int cur = p & 1;
    const size_t curo = (size_t)cur * HB;
    const size_t prvo = (size_t)(cur ^ 1) * HB;
    const bool do1 = (p < Tt);
    const bool do2 = (p > 0);

    f32x4 acc1 = {0.f, 0.f, 0.f, 0.f};
    f32x4 acc2 = {0.f, 0.f, 0.f, 0.f};

    if (do1) {
      // x_t @ w_ih1^T   (x fp32, converted inline)
      const float* xr = x + (size_t)arow * (Tt * (size_t)Ii) + (size_t)p * Ii + lk8;
      #pragma unroll
      for (int kc = 0; kc < Ii / 32; ++kc) {
        float4 xa = *(const float4*)(xr + kc * 32);
        float4 xb = *(const float4*)(xr + kc * 32 + 4);
        f16x8 a = { (f16)xa.x, (f16)xa.y, (f16)xa.z, (f16)xa.w,
                    (f16)xb.x, (f16)xb.y, (f16)xb.z, (f16)xb.w };
        f16x8 b = *(const f16x8*)&ls_wih1[lcol][kc * 32 + lk8];
        acc1 = mfma16(a, b, acc1);
      }
    }
    if (do1 && do2) {
      // h1_{p-1} feeds BOTH w_hh1 (acc1) and w_ih2 (acc2): shared A-frags
      const f16* hr = h1base + prvo + (size_t)arow * Hh + lk8;
      #pragma unroll
      for (int kc = 0; kc < Hh / 32; ++kc) {
        f16x8 a = *(const f16x8*)(hr + kc * 32);
        acc1 = mfma16(a, *(const f16x8*)&ls_whh1[lcol][kc * 32 + lk8], acc1);
        acc2 = mfma16(a, *(const f16x8*)&ls_wih2[lcol][kc * 32 + lk8], acc2);
      }
    } else if (do2) {
      // p == T: only w_ih2 path
      const f16* hr = h1base + prvo + (size_t)arow * Hh + lk8;
      #pragma unroll
      for (int kc = 0; kc < Hh / 32; ++kc) {
        f16x8 a = *(const f16x8*)(hr + kc * 32);
        acc2 = mfma16(a, *(const f16x8*)&ls_wih2[lcol][kc * 32 + lk8], acc2);
      }
    }
    if (do2) {
      // h2_{p-2} @ w_hh2^T
      const f16* hr = h2base + curo + (size_t)arow * Hh + lk8;
      #pragma unroll
      for (int kc = 0; kc < Hh / 32; ++kc) {
        f16x8 a = *(const f16x8*)(hr + kc * 32);
        acc2 = mfma16(a, *(const f16x8*)&ls_whh2[lcol][kc * 32 + lk8], acc2);
      }
    }

    if (do1) {
      f16* ho = h1base + curo;
      #pragma unroll
      for (int r = 0; r < 4; ++r) {
        float v = fast_tanh(acc1[r] + bias1);
        ho[(size_t)(drow0 + r) * Hh + dcol] = (f16)v;
      }
    }
    if (do2) {
      f16* ho = h2base + prvo;
      #pragma unroll
      for (int r = 0; r < 4; ++r) {
        float v = fast_tanh(acc2[r] + bias2);
        ho[(size_t)(drow0 + r) * Hh + dcol] = (f16)v;
      }
    }

    // ---- grid barrier (monotonic counter, agent scope for cross-XCD) ----
    __syncthreads();                       // drains this block's stores (vmcnt 0)
    if (threadIdx.x == 0) {
      __hip_atomic_fetch_add(cnt, 1u, __ATOMIC_ACQ_REL, __HIP_MEMORY_SCOPE_AGENT);
      const unsigned tgt = (unsigned)(p + 1) * NBLK;
      while (__hip_atomic_load(cnt, __ATOMIC_ACQUIRE, __HIP_MEMORY_SCOPE_AGENT) < tgt) {
        __builtin_amdgcn_s_sleep(1);
      }
    }
    __syncthreads();
  }

  // ---- final: out = h2_{T-1} @ w_out^T + b_out  (h2 final is in buffer 1) ----
  {
    const f16* hf = h2base + HB;
    const int tid = threadIdx.x;
    if (tid < 2 * Cc) {
      const int r = blockIdx.x * 2 + tid / Cc;
      const int c = tid % Cc;
      const f16* hr = hf + (size_t)r * Hh;
      const float* wrow = w_out + (size_t)c * Hh;
      float s = b_out[c];
      #pragma unroll 8
      for (int k = 0; k < Hh; ++k) s += (float)hr[k] * wrow[k];
      out[r * Cc + c] = s;
    }
  }
}

extern "C" void kernel_launch(void* const* d_in, const int* in_sizes, int n_in,
                              void* d_out, int out_size, void* d_ws, size_t ws_size,
                              hipStream_t stream) {
  (void)in_sizes; (void)n_in; (void)out_size; (void)ws_size;
  const float* x     = (const float*)d_in[0];
  const float* w_ih1 = (const float*)d_in[1];
  const float* w_hh1 = (const float*)d_in[2];
  const float* b_ih1 = (const float*)d_in[3];
  const float* b_hh1 = (const float*)d_in[4];
  const float* w_ih2 = (const float*)d_in[5];
  const float* w_hh2 = (const float*)d_in[6];
  const float* b_ih2 = (const float*)d_in[7];
  const float* b_hh2 = (const float*)d_in[8];
  const float* w_out = (const float*)d_in[9];
  const float* b_out = (const float*)d_in[10];
  float* out = (float*)d_out;

  unsigned* cnt = (unsigned*)d_ws;
  f16* h1base = (f16*)((char*)d_ws + 1024);
  f16* h2base = h1base + 2 * (size_t)Bb * Hh;

  // zero barrier counter + both ping-pong state buffers (h_{-1} = 0)
  const size_t clear_bytes = 1024 + 4 * (size_t)Bb * Hh * sizeof(f16);
  hipMemsetAsync(d_ws, 0, clear_bytes, stream);

  hipLaunchKernelGGL(rnn_persistent, dim3(NBLK), dim3(256), 0, stream,
                     x, w_ih1, w_hh1, b_ih1, b_hh1,
                     w_ih2, w_hh2, b_ih2, b_hh2, w_out, b_out,
                     out, cnt, h1base, h2base);
}